// Round 14
// baseline (143.852 us; speedup 1.0000x reference)
//
#include <hip/hip_runtime.h>
#include <hip/hip_bf16.h>
#include <stdint.h>

// Flash attention B=4,H=8,S=2048,D=64 fp32 io, bf16 MFMA compute.
// Round 14: R13 (66us, raw v_exp_f32) + shared-K/V dual-Q: each wave carries
// TWO 16-row Q fragment sets; every K/V ds_read_b128 feeds 2 MFMAs -> LDS
// traffic per q-row halves. Within-block split-K (2 groups x 4 waves),
// per-group double-buffered 64-key tiles, R10-verified merge epilogue.
// __launch_bounds__(512,4) pins VGPR<=128 (2 blocks/CU with 64KB LDS).

typedef __bf16 bf16;
typedef __attribute__((ext_vector_type(8))) __bf16 bf16x8;
typedef __attribute__((ext_vector_type(4))) __bf16 bf16x4;
typedef __attribute__((ext_vector_type(4))) float floatx4;

#define SLEN 2048
#define DH   64
#define BR   64
#define BC   64
#define NKT  (SLEN / BC)      // 32 64-key tiles
#define NQT  (SLEN / BR)
#define BH_N 32
#define LOG2E 1.44269504088896341f

#define CHB_L  1024           // LDS chunk stride (8 rows x 128B)
#define IMGE_G 4096           // bf16 elements per image in global (8192 B)

#define AS1 __attribute__((address_space(1)))
#define AS3 __attribute__((address_space(3)))

static __device__ inline void gload_lds16(const void* g, void* l) {
    __builtin_amdgcn_global_load_lds((const AS1 uint32_t*)g, (AS3 uint32_t*)l, 16, 0, 0);
}

static __device__ inline float fexp2(float x) {
    return __builtin_amdgcn_exp2f(x);   // raw v_exp_f32 (R13-verified)
}

static_assert(BH_N == NQT, "prep kernel folds bh and qt onto one grid axis");

// logical key l (0..63) -> physical key within 64-key tile
static __device__ inline int phys_key(int l) {
    int h = l >> 5, l5 = l & 31, q = l5 >> 3, j = l5 & 7;
    return 32 * h + (j < 4 ? 4 * q + j : 16 + 4 * q + (j - 4));
}

// ---- prepass (R8/R13 verbatim): kv -> swizzled K/V LDS-images + flags ----
__global__ __launch_bounds__(256) void kv_prep(
    const float* __restrict__ kv, const float* __restrict__ mask,
    bf16* __restrict__ kvK, bf16* __restrict__ kvT, int* __restrict__ flags)
{
    __shared__ bf16 Tl[64 * 72];
    __shared__ int wany[4];
    const int kt = blockIdx.x, z = blockIdx.y;   // z = bh for kv, z = qt for mask
    const int t = threadIdx.x;

    float acc = 0.f;
#pragma unroll
    for (int i = 0; i < 4; ++i) {
        int f = i * 256 + t;
        int row = f >> 4, c4 = (f & 15) * 4;
        const float4 v = *(const float4*)(mask + (size_t)(z * BR + row) * SLEN + kt * BC + c4);
        acc = fmaxf(acc, fmaxf(fmaxf(fabsf(v.x), fabsf(v.y)), fmaxf(fabsf(v.z), fabsf(v.w))));
    }
    unsigned long long any = __ballot(acc != 0.f);
    if ((t & 63) == 0) wany[t >> 6] = (any != 0ull) ? 1 : 0;

    const float* src = kv + ((size_t)z * SLEN + kt * BC) * DH;
#pragma unroll
    for (int i = 0; i < 4; ++i) {
        int f = i * 256 + t;
        int key = f >> 4, d4 = (f & 15) * 4;
        float4 v = *(const float4*)(src + (size_t)key * DH + d4);
        bf16x4 b; b[0] = (bf16)v.x; b[1] = (bf16)v.y; b[2] = (bf16)v.z; b[3] = (bf16)v.w;
        *(bf16x4*)&Tl[key * 72 + d4] = b;
    }
    __syncthreads();
    if (t == 0) flags[z * NKT + kt] = wany[0] | wany[1] | wany[2] | wany[3];

    // K image: granule (chunk c, pos p, row rl): g = (p - rl - 4*(c&1)) & 7
    bf16* outK = kvK + ((size_t)z * NKT + kt) * IMGE_G;
#pragma unroll
    for (int i = 0; i < 2; ++i) {
        int G = i * 256 + t;
        int c = G >> 6, L = G & 63, rl = L >> 3, p = L & 7;
        int g = (p - rl - 4 * (c & 1)) & 7, key = 8 * c + rl;
        bf16x8 w = *(const bf16x8*)&Tl[key * 72 + g * 8];
        *(bf16x8*)(outK + (size_t)G * 8) = w;
    }
    // V image: rows = d, content = logical keys 8g..8g+7 gathered via phys_key
    bf16* outV = kvT + ((size_t)z * NKT + kt) * IMGE_G;
#pragma unroll
    for (int i = 0; i < 2; ++i) {
        int G = i * 256 + t;
        int c = G >> 6, L = G & 63, dl = L >> 3, p = L & 7;
        int g = (p - dl - 4 * (c & 1)) & 7, d = 8 * c + dl;
        bf16x8 w;
#pragma unroll
        for (int j = 0; j < 8; ++j)
            w[j] = Tl[phys_key(8 * g + j) * 72 + d];
        *(bf16x8*)(outV + (size_t)G * 8) = w;
    }
}

// ---- main fused attention: dual-Q shared reads, split-K, raw exp2 ----
__global__ __launch_bounds__(512, 4) void attn_fwd14(
    const float* __restrict__ q, const float* __restrict__ mask,
    const int* __restrict__ flags,
    const bf16* __restrict__ kvK, const bf16* __restrict__ kvT,
    float* __restrict__ out)
{
    // [group][parity][K 8KB | V 8KB] = 64 KiB; merge buffers overlay after loop
    __shared__ __align__(16) char smem[65536];

    const int bh = blockIdx.x;
    const int qt = blockIdx.y;          // 128-row q tile
    const int q0 = qt * 128;
    const int t = threadIdx.x;
    const int wave = t >> 6, lane = t & 63;   // wave in [0,8)
    const int grp = wave >> 2;          // key half
    const int w4 = wave & 3;            // 32-row q sub-tile
    const int ln16 = lane & 15, quad = lane >> 4;
    const int ln8 = ln16 & 7, hb = ln16 >> 3;

    // Two Q B-fragment sets (rows w4*32 + rs*16 + ln16), scale folded
    const float qscale = 0.125f * LOG2E;
    bf16x8 aq[2][2];
#pragma unroll
    for (int rs = 0; rs < 2; ++rs) {
        const float* qrow = q + ((size_t)bh * SLEN + q0 + w4 * 32 + rs * 16 + ln16) * DH;
#pragma unroll
        for (int kc = 0; kc < 2; ++kc) {
            float4 f0 = *(const float4*)(qrow + kc * 32 + quad * 8);
            float4 f1 = *(const float4*)(qrow + kc * 32 + quad * 8 + 4);
            bf16x8 a;
            a[0] = (bf16)(f0.x * qscale); a[1] = (bf16)(f0.y * qscale);
            a[2] = (bf16)(f0.z * qscale); a[3] = (bf16)(f0.w * qscale);
            a[4] = (bf16)(f1.x * qscale); a[5] = (bf16)(f1.y * qscale);
            a[6] = (bf16)(f1.z * qscale); a[7] = (bf16)(f1.w * qscale);
            aq[rs][kc] = a;
        }
    }

    // flag bitmask: rows w4*32..+32 lie in 64-row flag tile qt*2 + (w4>>1)
    const int fqt = qt * 2 + (w4 >> 1);
    unsigned fmask;
    {
        int ld = (lane < 32) ? flags[fqt * NKT + lane] : 0;
        fmask = (unsigned)__ballot(ld != 0);
    }

    // conflict-swizzled read offsets (R8/R13 pattern)
    const int kbase0 = hb * CHB_L + ln8 * 128 + (((quad + ln8 + 4 * hb) & 7) << 4);
    const int kbase1 = hb * CHB_L + ln8 * 128 + (((quad + 4 + ln8 + 4 * hb) & 7) << 4);

    floatx4 o[2][4];
#pragma unroll
    for (int rs = 0; rs < 2; ++rs)
#pragma unroll
        for (int dt = 0; dt < 4; ++dt) o[rs][dt] = (floatx4){0.f, 0.f, 0.f, 0.f};
    float m_run[2] = {-3.0e38f, -3.0e38f}, l_run[2] = {0.f, 0.f};

    const bf16* kvKb = kvK + (size_t)bh * NKT * IMGE_G;
    const bf16* kvTb = kvT + (size_t)bh * NKT * IMGE_G;
    const int kt0 = grp * (NKT / 2);
    char* Gb = smem + grp * 32768;      // [parity][K 8KB | V 8KB]

    // prologue: stage tile kt0 into parity 0 (each of 4 waves: 2K + 2V chunks)
    {
        const bf16* sK = kvKb + (size_t)kt0 * IMGE_G;
        const bf16* sV = kvTb + (size_t)kt0 * IMGE_G;
        gload_lds16(sK + (size_t)(2 * w4) * 512 + lane * 8,     Gb + (2 * w4) * CHB_L);
        gload_lds16(sK + (size_t)(2 * w4 + 1) * 512 + lane * 8, Gb + (2 * w4 + 1) * CHB_L);
        gload_lds16(sV + (size_t)(2 * w4) * 512 + lane * 8,     Gb + 8192 + (2 * w4) * CHB_L);
        gload_lds16(sV + (size_t)(2 * w4 + 1) * 512 + lane * 8, Gb + 8192 + (2 * w4 + 1) * CHB_L);
    }

    for (int e = 0; e < NKT / 2; ++e) {
        __syncthreads();   // drains vmcnt -> parity buf ready; prev compute done
        const int kt = kt0 + e;

        if (e + 1 < NKT / 2) {   // prefetch next tile into the other parity
            char* Bn = Gb + ((e + 1) & 1) * 16384;
            const bf16* sK = kvKb + (size_t)(kt + 1) * IMGE_G;
            const bf16* sV = kvTb + (size_t)(kt + 1) * IMGE_G;
            gload_lds16(sK + (size_t)(2 * w4) * 512 + lane * 8,     Bn + (2 * w4) * CHB_L);
            gload_lds16(sK + (size_t)(2 * w4 + 1) * 512 + lane * 8, Bn + (2 * w4 + 1) * CHB_L);
            gload_lds16(sV + (size_t)(2 * w4) * 512 + lane * 8,     Bn + 8192 + (2 * w4) * CHB_L);
            gload_lds16(sV + (size_t)(2 * w4 + 1) * 512 + lane * 8, Bn + 8192 + (2 * w4 + 1) * CHB_L);
        }

        const char* Kb = Gb + (e & 1) * 16384;
        const char* Vb = Kb + 8192;

        // S^T = K * Q^T for BOTH row-sets; each K read feeds 2 MFMAs
        floatx4 s[2][4];
#pragma unroll
        for (int nt = 0; nt < 4; ++nt) {
            bf16x8 a0 = *(const bf16x8*)(Kb + nt * 2048 + kbase0);
            bf16x8 a1 = *(const bf16x8*)(Kb + nt * 2048 + kbase1);
            floatx4 accA = (floatx4){0.f, 0.f, 0.f, 0.f};
            floatx4 accB = (floatx4){0.f, 0.f, 0.f, 0.f};
            accA = __builtin_amdgcn_mfma_f32_16x16x32_bf16(a0, aq[0][0], accA, 0, 0, 0);
            accB = __builtin_amdgcn_mfma_f32_16x16x32_bf16(a0, aq[1][0], accB, 0, 0, 0);
            accA = __builtin_amdgcn_mfma_f32_16x16x32_bf16(a1, aq[0][1], accA, 0, 0, 0);
            accB = __builtin_amdgcn_mfma_f32_16x16x32_bf16(a1, aq[1][1], accB, 0, 0, 0);
            s[0][nt] = accA;
            s[1][nt] = accB;
        }

        // mask add per row-set (usually skipped)
        if (fmask & (1u << kt)) {
#pragma unroll
            for (int rs = 0; rs < 2; ++rs) {
                const float* mrow = mask + (size_t)(q0 + w4 * 32 + rs * 16 + ln16) * SLEN + kt * BC;
#pragma unroll
                for (int nt = 0; nt < 4; ++nt) {
                    float4 mv = *(const float4*)(mrow + 16 * nt + quad * 4);
                    s[rs][nt][0] += mv.x * LOG2E; s[rs][nt][1] += mv.y * LOG2E;
                    s[rs][nt][2] += mv.z * LOG2E; s[rs][nt][3] += mv.w * LOG2E;
                }
            }
        }

        // online softmax per row-set (independent chains -> ILP)
        bf16x8 pf[2][2];
#pragma unroll
        for (int rs = 0; rs < 2; ++rs) {
            float t01 = fmaxf(fmaxf(s[rs][0][0], s[rs][0][1]), fmaxf(s[rs][0][2], s[rs][0][3]));
            float t23 = fmaxf(fmaxf(s[rs][1][0], s[rs][1][1]), fmaxf(s[rs][1][2], s[rs][1][3]));
            float t45 = fmaxf(fmaxf(s[rs][2][0], s[rs][2][1]), fmaxf(s[rs][2][2], s[rs][2][3]));
            float t67 = fmaxf(fmaxf(s[rs][3][0], s[rs][3][1]), fmaxf(s[rs][3][2], s[rs][3][3]));
            float tmax = fmaxf(fmaxf(t01, t23), fmaxf(t45, t67));
            tmax = fmaxf(tmax, __shfl_xor(tmax, 16));
            tmax = fmaxf(tmax, __shfl_xor(tmax, 32));
            float mnew = fmaxf(m_run[rs], tmax);
            unsigned long long grew = __ballot(mnew > m_run[rs]);
            float alpha = fexp2(m_run[rs] - mnew);
            m_run[rs] = mnew;

            float rsum = 0.f;
#pragma unroll
            for (int r = 0; r < 4; ++r) {
                float p0 = fexp2(s[rs][0][r] - mnew);
                float p1 = fexp2(s[rs][1][r] - mnew);
                float p2 = fexp2(s[rs][2][r] - mnew);
                float p3 = fexp2(s[rs][3][r] - mnew);
                rsum += (p0 + p1) + (p2 + p3);
                pf[rs][0][r] = (bf16)p0; pf[rs][0][4 + r] = (bf16)p1;
                pf[rs][1][r] = (bf16)p2; pf[rs][1][4 + r] = (bf16)p3;
            }
            rsum += __shfl_xor(rsum, 16);
            rsum += __shfl_xor(rsum, 32);

            if (grew) {
                l_run[rs] = l_run[rs] * alpha + rsum;
                float a0 = __shfl(alpha, quad * 4 + 0);
                float a1 = __shfl(alpha, quad * 4 + 1);
                float a2 = __shfl(alpha, quad * 4 + 2);
                float a3 = __shfl(alpha, quad * 4 + 3);
#pragma unroll
                for (int dt = 0; dt < 4; ++dt) {
                    o[rs][dt][0] *= a0; o[rs][dt][1] *= a1;
                    o[rs][dt][2] *= a2; o[rs][dt][3] *= a3;
                }
            } else {
                l_run[rs] += rsum;
            }
        }

        // O += P V for BOTH row-sets; each V read feeds 2 MFMAs
#pragma unroll
        for (int dt = 0; dt < 4; ++dt) {
            bf16x8 v0 = *(const bf16x8*)(Vb + dt * 2048 + kbase0);
            bf16x8 v1 = *(const bf16x8*)(Vb + dt * 2048 + kbase1);
            o[0][dt] = __builtin_amdgcn_mfma_f32_16x16x32_bf16(pf[0][0], v0, o[0][dt], 0, 0, 0);
            o[1][dt] = __builtin_amdgcn_mfma_f32_16x16x32_bf16(pf[1][0], v0, o[1][dt], 0, 0, 0);
            o[0][dt] = __builtin_amdgcn_mfma_f32_16x16x32_bf16(pf[0][1], v1, o[0][dt], 0, 0, 0);
            o[1][dt] = __builtin_amdgcn_mfma_f32_16x16x32_bf16(pf[1][1], v1, o[1][dt], 0, 0, 0);
        }
    }

    // ---- epilogue: merge the two key-halves via LDS (R10-verified math) ----
    __syncthreads();   // all epochs done; staging LDS dead
    float* Xo  = (float*)smem;             // [128 rows][64 cols] = 32 KB
    float* Xml = (float*)(smem + 32768);   // [128][2] (m, l) = 1 KB

    if (grp == 1) {
#pragma unroll
        for (int rs = 0; rs < 2; ++rs) {
            int base = w4 * 32 + rs * 16;
#pragma unroll
            for (int dt = 0; dt < 4; ++dt) {
                int col = ln16 + 16 * dt;
                Xo[(base + quad * 4 + 0) * 64 + col] = o[rs][dt][0];
                Xo[(base + quad * 4 + 1) * 64 + col] = o[rs][dt][1];
                Xo[(base + quad * 4 + 2) * 64 + col] = o[rs][dt][2];
                Xo[(base + quad * 4 + 3) * 64 + col] = o[rs][dt][3];
            }
            Xml[(base + ln16) * 2 + 0] = m_run[rs];   // 4 quads same value — benign
            Xml[(base + ln16) * 2 + 1] = l_run[rs];
        }
    }
    __syncthreads();
    if (grp == 0) {
#pragma unroll
        for (int rs = 0; rs < 2; ++rs) {
            int base = w4 * 32 + rs * 16;
            float* ob = out + ((size_t)bh * SLEN + q0 + base) * DH;
#pragma unroll
            for (int r = 0; r < 4; ++r) {
                int row = quad * 4 + r;
                float m0 = __shfl(m_run[rs], row);
                float l0 = __shfl(l_run[rs], row);
                float m1 = Xml[(base + row) * 2 + 0];
                float l1 = Xml[(base + row) * 2 + 1];
                float M  = fmaxf(m0, m1);
                float a0 = fexp2(m0 - M), a1 = fexp2(m1 - M);
                float inv = 1.f / (l0 * a0 + l1 * a1);
#pragma unroll
                for (int dt = 0; dt < 4; ++dt) {
                    int col = ln16 + 16 * dt;
                    ob[row * DH + col] =
                        (o[rs][dt][r] * a0 + Xo[(base + row) * 64 + col] * a1) * inv;
                }
            }
        }
    }
}

// ---- legacy fallback (round-1 kernel) if ws is too small for the prepass ----
#define LDT 72
__global__ __launch_bounds__(256) void attn_mask_flags(
    const float* __restrict__ mask, int* __restrict__ flags)
{
    const int kt = blockIdx.x, qt = blockIdx.y;
    const int t = threadIdx.x;
    float acc = 0.f;
#pragma unroll
    for (int i = 0; i < 4; ++i) {
        int f = i * 256 + t;
        int row = f >> 4, c4 = (f & 15) * 4;
        const float4 v = *(const float4*)(mask + (size_t)(qt * BR + row) * SLEN + kt * BC + c4);
        acc = fmaxf(acc, fmaxf(fmaxf(fabsf(v.x), fabsf(v.y)), fmaxf(fabsf(v.z), fabsf(v.w))));
    }
    unsigned long long any = __ballot(acc != 0.f);
    __shared__ int wany[4];
    if ((t & 63) == 0) wany[t >> 6] = (any != 0ull) ? 1 : 0;
    __syncthreads();
    if (t == 0) flags[qt * NKT + kt] = wany[0] | wany[1] | wany[2] | wany[3];
}

__global__ __launch_bounds__(256) void attn_fwd(
    const float* __restrict__ q, const float* __restrict__ kv,
    const float* __restrict__ mask, const int* __restrict__ flags,
    float* __restrict__ out)
{
    __shared__ __align__(16) bf16 Kl[BC * LDT];
    __shared__ __align__(16) bf16 Vt[DH * LDT];
    __shared__ __align__(16) bf16 Pl[BR * LDT];

    const int qt = blockIdx.x;
    const int bh = blockIdx.y;
    const int q0 = qt * BR;
    const int t = threadIdx.x;
    const int wave = t >> 6, lane = t & 63;
    const int ln16 = lane & 15, quad = lane >> 4;

    const float qscale = 0.125f * LOG2E;
    bf16x8 aq[2];
    {
        const float* qrow = q + ((size_t)bh * SLEN + q0 + wave * 16 + ln16) * DH;
#pragma unroll
        for (int kc = 0; kc < 2; ++kc) {
            float4 f0 = *(const float4*)(qrow + kc * 32 + quad * 8);
            float4 f1 = *(const float4*)(qrow + kc * 32 + quad * 8 + 4);
            bf16x8 a;
            a[0] = (bf16)(f0.x * qscale); a[1] = (bf16)(f0.y * qscale);
            a[2] = (bf16)(f0.z * qscale); a[3] = (bf16)(f0.w * qscale);
            a[4] = (bf16)(f1.x * qscale); a[5] = (bf16)(f1.y * qscale);
            a[6] = (bf16)(f1.z * qscale); a[7] = (bf16)(f1.w * qscale);
            aq[kc] = a;
        }
    }

    floatx4 o[4];
#pragma unroll
    for (int dt = 0; dt < 4; ++dt) o[dt] = (floatx4){0.f, 0.f, 0.f, 0.f};
    float m_run[4], l_run[4];
#pragma unroll
    for (int r = 0; r < 4; ++r) { m_run[r] = -3.0e38f; l_run[r] = 0.f; }

    const float* kvb = kv + (size_t)bh * SLEN * DH;

    for (int kt = 0; kt < NKT; ++kt) {
        float4 st[4];
        const float* kvt = kvb + (size_t)kt * BC * DH;
#pragma unroll
        for (int i = 0; i < 4; ++i) {
            int f = i * 256 + t;
            st[i] = *(const float4*)(kvt + (size_t)f * 4);
        }
        __syncthreads();
#pragma unroll
        for (int i = 0; i < 4; ++i) {
            int f = i * 256 + t;
            int key = f >> 4, d4 = (f & 15) * 4;
            bf16 b0 = (bf16)st[i].x, b1 = (bf16)st[i].y, b2 = (bf16)st[i].z, b3 = (bf16)st[i].w;
            *(bf16x4*)&Kl[key * LDT + d4] = (bf16x4){b0, b1, b2, b3};
            Vt[(d4 + 0) * LDT + key] = b0;
            Vt[(d4 + 1) * LDT + key] = b1;
            Vt[(d4 + 2) * LDT + key] = b2;
            Vt[(d4 + 3) * LDT + key] = b3;
        }
        __syncthreads();

        floatx4 s[4];
#pragma unroll
        for (int nt = 0; nt < 4; ++nt) {
            s[nt] = (floatx4){0.f, 0.f, 0.f, 0.f};
#pragma unroll
            for (int kc = 0; kc < 2; ++kc) {
                bf16x8 bk = *(const bf16x8*)&Kl[(ln16 + 16 * nt) * LDT + kc * 32 + quad * 8];
                s[nt] = __builtin_amdgcn_mfma_f32_16x16x32_bf16(aq[kc], bk, s[nt], 0, 0, 0);
            }
        }

        if (!flags || flags[qt * NKT + kt]) {
            const float* mrow = mask + (size_t)(q0 + quad * 4) * SLEN + kt * BC + ln16;
#pragma unroll
            for (int r = 0; r < 4; ++r)
#pragma unroll
                for (int nt = 0; nt < 4; ++nt)
                    s[nt][r] += mrow[(size_t)r * SLEN + nt * 16] * LOG2E;
        }

#pragma unroll
        for (int r = 0; r < 4; ++r) {
            float mx = fmaxf(fmaxf(s[0][r], s[1][r]), fmaxf(s[2][r], s[3][r]));
            mx = fmaxf(mx, __shfl_xor(mx, 1));
            mx = fmaxf(mx, __shfl_xor(mx, 2));
            mx = fmaxf(mx, __shfl_xor(mx, 4));
            mx = fmaxf(mx, __shfl_xor(mx, 8));
            float mnew = fmaxf(m_run[r], mx);
            float alpha = exp2f(m_run[r] - mnew);
            m_run[r] = mnew;
            float rs = 0.f;
#pragma unroll
            for (int nt = 0; nt < 4; ++nt) {
                float p = exp2f(s[nt][r] - mnew);
                s[nt][r] = p;
                rs += p;
            }
            rs += __shfl_xor(rs, 1);
            rs += __shfl_xor(rs, 2);
            rs += __shfl_xor(rs, 4);
            rs += __shfl_xor(rs, 8);
            l_run[r] = l_run[r] * alpha + rs;
#pragma unroll
            for (int dt = 0; dt < 4; ++dt) o[dt][r] *= alpha;
        }

#pragma unroll
        for (int nt = 0; nt < 4; ++nt)
#pragma unroll
            for (int r = 0; r < 4; ++r)
                Pl[(wave * 16 + quad * 4 + r) * LDT + ln16 + 16 * nt] = (bf16)s[nt][r];

#pragma unroll
        for (int kc2 = 0; kc2 < 2; ++kc2) {
            bf16x8 pfr = *(const bf16x8*)&Pl[(wave * 16 + ln16) * LDT + kc2 * 32 + quad * 8];
#pragma unroll
            for (int dt = 0; dt < 4; ++dt) {
                bf16x8 vfr = *(const bf16x8*)&Vt[(ln16 + 16 * dt) * LDT + kc2 * 32 + quad * 8];
                o[dt] = __builtin_amdgcn_mfma_f32_16x16x32_bf16(pfr, vfr, o[dt], 0, 0, 0);
            }
        }
    }

#pragma unroll
    for (int r = 0; r < 4; ++r) {
        float inv = 1.0f / l_run[r];
        int qrow = q0 + wave * 16 + quad * 4 + r;
        float* orow = out + ((size_t)bh * SLEN + qrow) * DH;
#pragma unroll
        for (int dt = 0; dt < 4; ++dt)
            orow[ln16 + 16 * dt] = o[dt][r] * inv;
    }
}

extern "C" void kernel_launch(void* const* d_in, const int* in_sizes, int n_in,
                              void* d_out, int out_size, void* d_ws, size_t ws_size,
                              hipStream_t stream)
{
    const float* q    = (const float*)d_in[0];
    const float* kv   = (const float*)d_in[1];
    const float* mask = (const float*)d_in[2];
    float* out = (float*)d_out;

    const size_t kvKoff = 4096;                                   // flags: 32*32*4
    const size_t kvToff = kvKoff + (size_t)BH_N * NKT * IMGE_G * 2;
    const size_t need   = kvToff + (size_t)BH_N * NKT * IMGE_G * 2;

    if (ws_size >= need) {
        int*  flags = (int*)d_ws;
        bf16* kvK   = (bf16*)((char*)d_ws + kvKoff);
        bf16* kvT   = (bf16*)((char*)d_ws + kvToff);
        kv_prep<<<dim3(NKT, BH_N), 256, 0, stream>>>(kv, mask, kvK, kvT, flags);
        attn_fwd14<<<dim3(BH_N, SLEN / 128), 512, 0, stream>>>(q, mask, flags, kvK, kvT, out);
    } else {
        int* flags = nullptr;
        if (ws_size >= (size_t)NQT * NKT * sizeof(int)) {
            flags = (int*)d_ws;
            attn_mask_flags<<<dim3(NKT, NQT), 256, 0, stream>>>(mask, flags);
        }
        attn_fwd<<<dim3(NQT, BH_N), 256, 0, stream>>>(q, kv, mask, flags, out);
    }
}